// Round 1
// baseline (800.354 us; speedup 1.0000x reference)
//
#include <hip/hip_runtime.h>
#include <stdint.h>

typedef unsigned short u16;
typedef short bf16x8 __attribute__((ext_vector_type(8)));
typedef float f32x4 __attribute__((ext_vector_type(4)));

__device__ __forceinline__ u16 f2b(float f) {
  uint32_t u = __builtin_bit_cast(uint32_t, f);
  u += 0x7fffu + ((u >> 16) & 1u);
  return (u16)(u >> 16);
}

__device__ __forceinline__ void gload_lds16(const void* g, void* l) {
  __builtin_amdgcn_global_load_lds(
      (const __attribute__((address_space(1))) void*)g,
      (__attribute__((address_space(3))) void*)l, 16, 0, 0);
}

// ---------------- gate cumprod (30 elems) ----------------
__global__ void gate_kernel(const float* __restrict__ gl, float* __restrict__ gate) {
  if (threadIdx.x == 0 && blockIdx.x == 0) {
    float g = 1.0f;
    for (int i = 0; i < 30; ++i) {
      float s = 1.0f / (1.0f + __expf(-gl[i]));
      g *= (1.0f - s);
      gate[i] = g;
    }
  }
}

// ---------------- x fp32 -> bf16 ----------------
__global__ __launch_bounds__(256) void cvt_x_kernel(const float* __restrict__ x,
                                                    u16* __restrict__ xb) {
  int64_t i = ((int64_t)blockIdx.x * 256 + threadIdx.x) * 8;
  float4 a = *(const float4*)(x + i);
  float4 b = *(const float4*)(x + i + 4);
  union { u16 u[8]; bf16x8 v; } o;
  o.u[0] = f2b(a.x); o.u[1] = f2b(a.y); o.u[2] = f2b(a.z); o.u[3] = f2b(a.w);
  o.u[4] = f2b(b.x); o.u[5] = f2b(b.y); o.u[6] = f2b(b.z); o.u[7] = f2b(b.w);
  *(bf16x8*)(xb + i) = o.v;
}

// ---------------- W [1024][1024] fp32 -> W^T bf16 ----------------
__global__ __launch_bounds__(256) void transpose_w_kernel(const float* __restrict__ src,
                                                          u16* __restrict__ dst) {
  __shared__ float ls[64][65];
  int t = threadIdx.x;
  int bx = blockIdx.x & 15;   // src col tile
  int by = blockIdx.x >> 4;   // src row tile
  int r0 = by * 64, c0 = bx * 64;
  int tr = t >> 6, tc = t & 63;
#pragma unroll
  for (int i = 0; i < 16; ++i)
    ls[tr + i * 4][tc] = src[(int64_t)(r0 + tr + i * 4) * 1024 + c0 + tc];
  __syncthreads();
#pragma unroll
  for (int i = 0; i < 16; ++i)
    dst[(int64_t)(c0 + tr + i * 4) * 1024 + r0 + tc] = f2b(ls[tc][tr + i * 4]);
}

// ---------------- q = (q_tok @ Wq) * log2e/temp, bf16 [H][64][64] ----------------
__global__ __launch_bounds__(256) void q_kernel(const float* __restrict__ q_tok,
                                                const float* __restrict__ Wq,
                                                u16* __restrict__ qb) {
  __shared__ float Qs[64][65];
  __shared__ float Ws[64][65];
  int h = blockIdx.x;
  int t = threadIdx.x;
  int tn = t >> 4, tk = t & 15;
  float acc[4][4] = {};
  for (int dt = 0; dt < 16; ++dt) {
    __syncthreads();
#pragma unroll
    for (int i = 0; i < 16; ++i) {
      int idx = t + i * 256;
      int rr = idx >> 6, cc = idx & 63;
      Qs[rr][cc] = q_tok[rr * 1024 + dt * 64 + cc];
      Ws[rr][cc] = Wq[(dt * 64 + rr) * 1024 + h * 64 + cc];
    }
    __syncthreads();
    for (int d = 0; d < 64; ++d) {
      float qv[4], wv[4];
#pragma unroll
      for (int i = 0; i < 4; ++i) qv[i] = Qs[tn * 4 + i][d];
#pragma unroll
      for (int j = 0; j < 4; ++j) wv[j] = Ws[d][tk * 4 + j];
#pragma unroll
      for (int i = 0; i < 4; ++i)
#pragma unroll
        for (int j = 0; j < 4; ++j) acc[i][j] += qv[i] * wv[j];
    }
  }
  const float sc = 1.44269504f / 8.0f;  // log2e / sqrt(dk)
#pragma unroll
  for (int i = 0; i < 4; ++i)
#pragma unroll
    for (int j = 0; j < 4; ++j)
      qb[(h * 64 + tn * 4 + i) * 64 + tk * 4 + j] = f2b(acc[i][j] * sc);
}

// ---------------- KV GEMM: [65536 x 1024] @ [1024 x 2048] ----------------
// A = x_bf16 row-major; B = wkvT [2048][1024] (B^T form). n<1024 -> k, else v.
// k written as [B][H][L][64]; v written TRANSPOSED as [B][H][64][L] via swapped MFMA.
__global__ __launch_bounds__(256) void kv_gemm_kernel(
    const u16* __restrict__ xb, const u16* __restrict__ wkvT,
    const float* __restrict__ gate, u16* __restrict__ kbuf, u16* __restrict__ vT) {
  __shared__ u16 As[4096];  // [128][32]
  __shared__ u16 Bs[4096];  // [128 n][32]
  int bid = blockIdx.x;
  int mb = bid >> 4, nb = bid & 15;
  int m0 = mb * 128, n0 = nb * 128;
  int t = threadIdx.x, w = t >> 6, lane = t & 63;
  int wm = (w >> 1) * 64, wn = (w & 1) * 64;
  bool isV = (n0 >= 1024);
  f32x4 acc[4][4] = {};
  int srow = w * 32 + (lane >> 2);
  int scol = (lane & 3) * 8;
  const u16* aSrc = xb + (int64_t)(m0 + srow) * 1024 + scol;
  const u16* bSrc = wkvT + (int64_t)(n0 + srow) * 1024 + scol;
  u16* aDst = As + w * 1024;
  u16* bDst = Bs + w * 1024;
  for (int kt = 0; kt < 32; ++kt) {
    __syncthreads();
    int ko = kt * 32;
    gload_lds16(aSrc + ko, aDst);
    gload_lds16(aSrc + 16 * 1024 + ko, aDst + 512);
    gload_lds16(bSrc + ko, bDst);
    gload_lds16(bSrc + 16 * 1024 + ko, bDst + 512);
    __syncthreads();
    int l15 = lane & 15, lh = (lane >> 4) * 8;
    bf16x8 af[4], bf[4];
#pragma unroll
    for (int i = 0; i < 4; ++i) af[i] = *(const bf16x8*)(As + (wm + i * 16 + l15) * 32 + lh);
#pragma unroll
    for (int j = 0; j < 4; ++j) bf[j] = *(const bf16x8*)(Bs + (wn + j * 16 + l15) * 32 + lh);
    if (!isV) {
#pragma unroll
      for (int i = 0; i < 4; ++i)
#pragma unroll
        for (int j = 0; j < 4; ++j)
          acc[i][j] = __builtin_amdgcn_mfma_f32_16x16x32_bf16(af[i], bf[j], acc[i][j], 0, 0, 0);
    } else {
      // transposed output: D rows = n (weight cols), D cols = m (x rows)
#pragma unroll
      for (int i = 0; i < 4; ++i)
#pragma unroll
        for (int j = 0; j < 4; ++j)
          acc[i][j] = __builtin_amdgcn_mfma_f32_16x16x32_bf16(bf[i], af[j], acc[i][j], 0, 0, 0);
    }
  }
  int b = m0 >> 11, lbase = m0 & 2047;
  int l15 = lane & 15, lr = (lane >> 4) * 4;
  if (!isV) {
#pragma unroll
    for (int i = 0; i < 4; ++i)
#pragma unroll
      for (int j = 0; j < 4; ++j) {
        int gcol = n0 + wn + j * 16 + l15;
        int h = gcol >> 6, dk = gcol & 63;
#pragma unroll
        for (int r = 0; r < 4; ++r) {
          int l = lbase + wm + i * 16 + lr + r;
          kbuf[(int64_t)((b * 16 + h) * 2048 + l) * 64 + dk] = f2b(acc[i][j][r]);
        }
      }
  } else {
#pragma unroll
    for (int j = 0; j < 4; ++j) {
      int lloc = wm + j * 16 + l15;
      int l = lbase + lloc;
      float g = 1.0f;
      if (lbase == 0 && lloc < 30) g = gate[lloc];
#pragma unroll
      for (int i = 0; i < 4; ++i) {
#pragma unroll
        for (int r = 0; r < 4; ++r) {
          int gn = (n0 - 1024) + wn + i * 16 + lr + r;
          int h = gn >> 6, dv = gn & 63;
          vT[(int64_t)((b * 16 + h) * 64 + dv) * 2048 + l] = f2b(acc[i][j][r] * g);
        }
      }
    }
  }
}

// ---------------- fused flash attention: block = (b,h); wave owns 16 q-rows ----------------
__global__ __launch_bounds__(256) void attn_kernel(
    const u16* __restrict__ qb, const u16* __restrict__ kbuf,
    const u16* __restrict__ vT, u16* __restrict__ attnout) {
  __shared__ u16 Ps[4096];  // per-wave 1 KB (16 rows x 64 l), XOR-swizzled
  int bid = blockIdx.x;
  int b = bid >> 4, h = bid & 15;
  int t = threadIdx.x, w = t >> 6, lane = t & 63;
  int l15 = lane & 15, lh8 = (lane >> 4) * 8;
  bf16x8 qf0 = *(const bf16x8*)(qb + (h * 64 + w * 16 + l15) * 64 + lh8);
  bf16x8 qf1 = *(const bf16x8*)(qb + (h * 64 + w * 16 + l15) * 64 + 32 + lh8);
  const u16* kB = kbuf + (int64_t)(b * 16 + h) * (2048 * 64);
  const u16* vB = vT + (int64_t)(b * 16 + h) * (64 * 2048);
  char* PsW = (char*)Ps + w * 2048;
  float m_r[4] = {-1e30f, -1e30f, -1e30f, -1e30f};
  float s_r[4] = {0.f, 0.f, 0.f, 0.f};
  f32x4 O[4] = {};
  for (int lt = 0; lt < 32; ++lt) {
    int l0 = lt * 64;
    f32x4 S[4];
#pragma unroll
    for (int ls = 0; ls < 4; ++ls) {
      const u16* kr = kB + (l0 + ls * 16 + l15) * 64 + lh8;
      bf16x8 k0 = *(const bf16x8*)(kr);
      bf16x8 k1 = *(const bf16x8*)(kr + 32);
      f32x4 s = {};
      s = __builtin_amdgcn_mfma_f32_16x16x32_bf16(qf0, k0, s, 0, 0, 0);
      s = __builtin_amdgcn_mfma_f32_16x16x32_bf16(qf1, k1, s, 0, 0, 0);
      S[ls] = s;
    }
    float scale[4];
#pragma unroll
    for (int r = 0; r < 4; ++r) {
      float tm = fmaxf(fmaxf(S[0][r], S[1][r]), fmaxf(S[2][r], S[3][r]));
#pragma unroll
      for (int msk = 1; msk < 16; msk <<= 1)
        tm = fmaxf(tm, __shfl_xor(tm, msk, 16));
      float mn = fmaxf(m_r[r], tm);
      scale[r] = exp2f(m_r[r] - mn);
      m_r[r] = mn;
    }
#pragma unroll
    for (int ls = 0; ls < 4; ++ls)
#pragma unroll
      for (int r = 0; r < 4; ++r) S[ls][r] = exp2f(S[ls][r] - m_r[r]);
#pragma unroll
    for (int r = 0; r < 4; ++r) {
      float ps = (S[0][r] + S[1][r]) + (S[2][r] + S[3][r]);
      s_r[r] = s_r[r] * scale[r] + ps;
    }
    // P (D-layout) -> swizzled LDS rows so PV A-frags read b128 conflict-light
#pragma unroll
    for (int ls = 0; ls < 4; ++ls)
#pragma unroll
      for (int r = 0; r < 4; ++r) {
        int row = (lane >> 4) * 4 + r;
        int off = (ls * 16 + l15) * 2;
        *(u16*)(PsW + row * 128 + (off ^ ((row & 7) << 4))) = f2b(S[ls][r]);
      }
#pragma unroll
    for (int d = 0; d < 4; ++d)
#pragma unroll
      for (int r = 0; r < 4; ++r) O[d][r] *= scale[r];
    bf16x8 pa0, pa1;
    {
      int off0 = (lane >> 4) * 16;
      pa0 = *(const bf16x8*)(PsW + l15 * 128 + (off0 ^ ((l15 & 7) << 4)));
      pa1 = *(const bf16x8*)(PsW + l15 * 128 + ((off0 + 64) ^ ((l15 & 7) << 4)));
    }
#pragma unroll
    for (int d = 0; d < 4; ++d) {
      const u16* vr = vB + (d * 16 + l15) * 2048 + l0 + lh8;
      bf16x8 v0 = *(const bf16x8*)(vr);
      bf16x8 v1 = *(const bf16x8*)(vr + 32);
      O[d] = __builtin_amdgcn_mfma_f32_16x16x32_bf16(pa0, v0, O[d], 0, 0, 0);
      O[d] = __builtin_amdgcn_mfma_f32_16x16x32_bf16(pa1, v1, O[d], 0, 0, 0);
    }
  }
#pragma unroll
  for (int r = 0; r < 4; ++r) {
    float s = s_r[r];
#pragma unroll
    for (int msk = 1; msk < 16; msk <<= 1) s += __shfl_xor(s, msk, 16);
    float inv = 1.0f / s;
#pragma unroll
    for (int d = 0; d < 4; ++d) O[d][r] *= inv;
  }
#pragma unroll
  for (int d = 0; d < 4; ++d)
#pragma unroll
    for (int r = 0; r < 4; ++r) {
      int n = w * 16 + (lane >> 4) * 4 + r;
      attnout[(int64_t)(b * 64 + n) * 1024 + h * 64 + d * 16 + l15] = f2b(O[d][r]);
    }
}

// ---------------- FC GEMM [2048 x 1024] @ [1024 x 1024] + q_tok residual ----------------
__global__ __launch_bounds__(256) void fc_gemm_kernel(
    const u16* __restrict__ a, const u16* __restrict__ bT,
    const float* __restrict__ q_tok, float* __restrict__ out) {
  __shared__ u16 As[4096];
  __shared__ u16 Bs[4096];
  int bid = blockIdx.x;
  int mb = bid >> 3, nb = bid & 7;
  int m0 = mb * 128, n0 = nb * 128;
  int t = threadIdx.x, w = t >> 6, lane = t & 63;
  int wm = (w >> 1) * 64, wn = (w & 1) * 64;
  f32x4 acc[4][4] = {};
  int srow = w * 32 + (lane >> 2);
  int scol = (lane & 3) * 8;
  const u16* aSrc = a + (int64_t)(m0 + srow) * 1024 + scol;
  const u16* bSrc = bT + (int64_t)(n0 + srow) * 1024 + scol;
  u16* aDst = As + w * 1024;
  u16* bDst = Bs + w * 1024;
  for (int kt = 0; kt < 32; ++kt) {
    __syncthreads();
    int ko = kt * 32;
    gload_lds16(aSrc + ko, aDst);
    gload_lds16(aSrc + 16 * 1024 + ko, aDst + 512);
    gload_lds16(bSrc + ko, bDst);
    gload_lds16(bSrc + 16 * 1024 + ko, bDst + 512);
    __syncthreads();
    int l15 = lane & 15, lh = (lane >> 4) * 8;
    bf16x8 af[4], bf[4];
#pragma unroll
    for (int i = 0; i < 4; ++i) af[i] = *(const bf16x8*)(As + (wm + i * 16 + l15) * 32 + lh);
#pragma unroll
    for (int j = 0; j < 4; ++j) bf[j] = *(const bf16x8*)(Bs + (wn + j * 16 + l15) * 32 + lh);
#pragma unroll
    for (int i = 0; i < 4; ++i)
#pragma unroll
      for (int j = 0; j < 4; ++j)
        acc[i][j] = __builtin_amdgcn_mfma_f32_16x16x32_bf16(af[i], bf[j], acc[i][j], 0, 0, 0);
  }
  int l15 = lane & 15, lr = (lane >> 4) * 4;
#pragma unroll
  for (int i = 0; i < 4; ++i)
#pragma unroll
    for (int j = 0; j < 4; ++j) {
      int col = n0 + wn + j * 16 + l15;
#pragma unroll
      for (int r = 0; r < 4; ++r) {
        int row = m0 + wm + i * 16 + lr + r;
        out[(int64_t)row * 1024 + col] = acc[i][j][r] + q_tok[(row & 63) * 1024 + col];
      }
    }
}

// ---------------- LayerNorm over last dim (1024), eps=1e-6 ----------------
__global__ __launch_bounds__(256) void ln_kernel(
    const float* __restrict__ fc, const float* __restrict__ gamma,
    const float* __restrict__ beta, float* __restrict__ out) {
  __shared__ float red[8];
  int row = blockIdx.x, t = threadIdx.x;
  float4 y = *(const float4*)(fc + (int64_t)row * 1024 + t * 4);
  float s = (y.x + y.y) + (y.z + y.w);
  float ss = (y.x * y.x + y.y * y.y) + (y.z * y.z + y.w * y.w);
#pragma unroll
  for (int msk = 1; msk < 64; msk <<= 1) {
    s += __shfl_xor(s, msk, 64);
    ss += __shfl_xor(ss, msk, 64);
  }
  if ((t & 63) == 0) { red[t >> 6] = s; red[4 + (t >> 6)] = ss; }
  __syncthreads();
  s = (red[0] + red[1]) + (red[2] + red[3]);
  ss = (red[4] + red[5]) + (red[6] + red[7]);
  float mu = s * (1.0f / 1024.0f);
  float var = ss * (1.0f / 1024.0f) - mu * mu;
  float rstd = rsqrtf(var + 1e-6f);
  float4 g = *(const float4*)(gamma + t * 4);
  float4 be = *(const float4*)(beta + t * 4);
  float4 o;
  o.x = (y.x - mu) * rstd * g.x + be.x;
  o.y = (y.y - mu) * rstd * g.y + be.y;
  o.z = (y.z - mu) * rstd * g.z + be.z;
  o.w = (y.w - mu) * rstd * g.w + be.w;
  *(float4*)(out + (int64_t)row * 1024 + t * 4) = o;
}

extern "C" void kernel_launch(void* const* d_in, const int* in_sizes, int n_in,
                              void* d_out, int out_size, void* d_ws, size_t ws_size,
                              hipStream_t stream) {
  const float* x     = (const float*)d_in[0];
  const float* q_tok = (const float*)d_in[1];
  const float* Wq    = (const float*)d_in[2];
  const float* Wk    = (const float*)d_in[3];
  const float* Wv    = (const float*)d_in[4];
  const float* Wfc   = (const float*)d_in[5];
  const float* gl    = (const float*)d_in[6];
  const float* gamma = (const float*)d_in[7];
  const float* beta  = (const float*)d_in[8];
  float* out = (float*)d_out;
  char* ws = (char*)d_ws;

  u16*   xb      = (u16*)(ws);                    // 134,217,728 B
  u16*   kbuf    = (u16*)(ws + 134217728);        // 134,217,728 B  [B][H][L][64]
  u16*   vT      = (u16*)(ws + 268435456);        // 134,217,728 B  [B][H][64][L]
  u16*   wkvT    = (u16*)(ws + 402653184);        // 4,194,304 B    [2048][1024]
  u16*   wfcT    = (u16*)(ws + 406847488);        // 2,097,152 B    [1024][1024]
  u16*   qb      = (u16*)(ws + 408944640);        // 131,072 B      [16][64][64]
  float* gate    = (float*)(ws + 409075712);      // 512 B
  u16*   attnout = (u16*)(ws + 409076224);        // 4,194,304 B    [2048][1024]
  float* fcout   = (float*)(ws + 413270528);      // 8,388,608 B

  gate_kernel<<<1, 64, 0, stream>>>(gl, gate);
  cvt_x_kernel<<<32768, 256, 0, stream>>>(x, xb);
  transpose_w_kernel<<<256, 256, 0, stream>>>(Wk, wkvT);
  transpose_w_kernel<<<256, 256, 0, stream>>>(Wv, wkvT + 1024 * 1024);
  transpose_w_kernel<<<256, 256, 0, stream>>>(Wfc, wfcT);
  q_kernel<<<16, 256, 0, stream>>>(q_tok, Wq, qb);
  kv_gemm_kernel<<<8192, 256, 0, stream>>>(xb, wkvT, gate, kbuf, vT);
  attn_kernel<<<512, 256, 0, stream>>>(qb, kbuf, vT, attnout);
  fc_gemm_kernel<<<128, 256, 0, stream>>>(attnout, wfcT, q_tok, fcout);
  ln_kernel<<<2048, 256, 0, stream>>>(fcout, gamma, beta, out);
}